// Round 1
// baseline (525.922 us; speedup 1.0000x reference)
//
#include <hip/hip_runtime.h>

// FANS neural state update: B=131072 rows, 16 independent MLPs (12->64->64->1, tanh).
// Compute-bound fp32 (no fp32 MFMA on CDNA4): floor ~132us FMA + ~37us tanh.
// Layout: blockIdx.y = state s, 1 row/thread, weights for state s staged in LDS
// (19.7KB), read via broadcast (all lanes same address -> conflict-free).

#define N_STATES 16
#define N_FEAT   64
#define ZIN      12
#define W0_PER_S (N_FEAT * ZIN)      // 768
#define W1_PER_S (N_FEAT * N_FEAT)   // 4096
#define W2_PER_S (N_FEAT)            // 64

__device__ __forceinline__ float fast_tanh(float x) {
    // tanh(x) = 1 - 2/(exp(2x)+1); exp(2x) = exp2(x * 2*log2(e))
    float e = __builtin_amdgcn_exp2f(x * 2.885390081777927f);
    float r = __builtin_amdgcn_rcpf(e + 1.0f);
    return __builtin_fmaf(-2.0f, r, 1.0f);   // 1 - 2r
}

__global__ __launch_bounds__(256) void fans_kernel(
    const float* __restrict__ x_f, const float* __restrict__ x_b,
    const float* __restrict__ u,   const float* __restrict__ W0,
    const float* __restrict__ W1,  const float* __restrict__ W2,
    float* __restrict__ out, int nb)
{
    __shared__ __align__(16) float smem[W0_PER_S + W1_PER_S + W2_PER_S];
    float* sW0 = smem;
    float* sW1 = smem + W0_PER_S;
    float* sW2 = smem + W0_PER_S + W1_PER_S;

    const int s   = blockIdx.y;
    const int tid = threadIdx.x;

    // ---- stage this state's weights into LDS (coalesced) ----
    {
        const float* w0 = W0 + s * W0_PER_S;
        #pragma unroll
        for (int k = 0; k < 3; ++k) sW0[tid + 256 * k] = w0[tid + 256 * k];
        const float* w1 = W1 + s * W1_PER_S;
        #pragma unroll
        for (int k = 0; k < 16; ++k) sW1[tid + 256 * k] = w1[tid + 256 * k];
        if (tid < 64) sW2[tid] = W2[s * W2_PER_S + tid];
    }
    __syncthreads();

    const int b = blockIdx.x * 256 + tid;
    if (b >= nb) return;

    // ---- build z[12]: 8 selected x_tilde entries (sorted IDX[s]) + 4 u ----
    // IDX[s] sorted = {0..wrap-1} ++ {s..15} with wrap = max(0, s-8);
    // entry j: idx = (j < wrap) ? j : s + j - wrap. idx<8 -> x_f, else x_b.
    float z[12];
    const int wrap = (s > 8) ? (s - 8) : 0;
    #pragma unroll
    for (int j = 0; j < 8; ++j) {
        int idx = (j < wrap) ? j : (s + j - wrap);   // wave-uniform
        z[j] = (idx < 8) ? x_f[b * 8 + idx] : x_b[b * 8 + (idx - 8)];
    }
    const float4 uv = *(const float4*)(u + b * 4);
    z[8] = uv.x; z[9] = uv.y; z[10] = uv.z; z[11] = uv.w;

    // ---- layer 1: h1[o] = tanh(sum_i z[i] * W0[s][o][i]) ----
    float h1[N_FEAT];
    #pragma unroll 8
    for (int o = 0; o < N_FEAT; ++o) {
        const float4* w = (const float4*)(sW0 + o * ZIN);  // 48B stride, 16B aligned
        float4 wa = w[0], wb = w[1], wc = w[2];
        float a0 = z[0] * wa.x;
        float a1 = z[1] * wa.y;
        float a2 = z[2] * wa.z;
        a0 = __builtin_fmaf(z[3],  wa.w, a0);
        a1 = __builtin_fmaf(z[4],  wb.x, a1);
        a2 = __builtin_fmaf(z[5],  wb.y, a2);
        a0 = __builtin_fmaf(z[6],  wb.z, a0);
        a1 = __builtin_fmaf(z[7],  wb.w, a1);
        a2 = __builtin_fmaf(z[8],  wc.x, a2);
        a0 = __builtin_fmaf(z[9],  wc.y, a0);
        a1 = __builtin_fmaf(z[10], wc.z, a1);
        a2 = __builtin_fmaf(z[11], wc.w, a2);
        h1[o] = fast_tanh(a0 + a1 + a2);
    }

    // ---- layer 2 + output dot: dx = sum_o tanh(<h1, W1[s][o]>) * W2[s][o] ----
    float dx = 0.0f;
    #pragma unroll 2
    for (int o = 0; o < N_FEAT; ++o) {
        const float4* w = (const float4*)(sW1 + o * N_FEAT);  // 256B aligned
        float a0 = 0.f, a1 = 0.f, a2 = 0.f, a3 = 0.f;
        #pragma unroll
        for (int q = 0; q < 16; ++q) {
            float4 wv = w[q];
            a0 = __builtin_fmaf(h1[4 * q + 0], wv.x, a0);
            a1 = __builtin_fmaf(h1[4 * q + 1], wv.y, a1);
            a2 = __builtin_fmaf(h1[4 * q + 2], wv.z, a2);
            a3 = __builtin_fmaf(h1[4 * q + 3], wv.w, a3);
        }
        float hv = fast_tanh((a0 + a1) + (a2 + a3));
        dx = __builtin_fmaf(hv, sW2[o], dx);
    }

    out[b * N_STATES + s] = dx;
}

extern "C" void kernel_launch(void* const* d_in, const int* in_sizes, int n_in,
                              void* d_out, int out_size, void* d_ws, size_t ws_size,
                              hipStream_t stream) {
    const float* x_f = (const float*)d_in[0];
    const float* x_b = (const float*)d_in[1];
    const float* u   = (const float*)d_in[2];
    const float* W0  = (const float*)d_in[3];
    const float* W1  = (const float*)d_in[4];
    const float* W2  = (const float*)d_in[5];
    float* out = (float*)d_out;

    const int nb = in_sizes[0] / 8;                 // B = 131072
    dim3 grid((nb + 255) / 256, N_STATES);
    fans_kernel<<<grid, 256, 0, stream>>>(x_f, x_b, u, W0, W1, W2, out, nb);
}

// Round 2
// 452.782 us; speedup vs baseline: 1.1615x; 1.1615x over previous
//
#include <hip/hip_runtime.h>

// FANS neural state update: B=131072 rows, 16 independent MLPs (12->64->64->1, tanh).
// Compute-bound fp32 (no fp32 MFMA on CDNA4).
// R1 post-mortem: `#pragma unroll 8` on layer 1 left h1[o] dynamically indexed ->
// h1 spilled to scratch (VGPR_Count=56, WRITE_SIZE 586MB vs 8.4MB ideal).
// R2 fix: fully unroll layer 1 so h1 is constant-indexed everywhere -> stays in VGPRs.
// Layer 2 stays a loop (constant inner indices) to keep code ~11KB (I-cache friendly).

#define N_STATES 16
#define N_FEAT   64
#define ZIN      12
#define W0_PER_S (N_FEAT * ZIN)      // 768
#define W1_PER_S (N_FEAT * N_FEAT)   // 4096
#define W2_PER_S (N_FEAT)            // 64

__device__ __forceinline__ float fast_tanh(float x) {
    // tanh(x) = 1 - 2/(exp(2x)+1); exp(2x) = exp2(x * 2*log2(e))
    float e = __builtin_amdgcn_exp2f(x * 2.885390081777927f);
    float r = __builtin_amdgcn_rcpf(e + 1.0f);
    return __builtin_fmaf(-2.0f, r, 1.0f);   // 1 - 2r
}

__global__ __launch_bounds__(256) void fans_kernel(
    const float* __restrict__ x_f, const float* __restrict__ x_b,
    const float* __restrict__ u,   const float* __restrict__ W0,
    const float* __restrict__ W1,  const float* __restrict__ W2,
    float* __restrict__ out, int nb)
{
    __shared__ __align__(16) float smem[W0_PER_S + W1_PER_S + W2_PER_S];
    float* sW0 = smem;
    float* sW1 = smem + W0_PER_S;
    float* sW2 = smem + W0_PER_S + W1_PER_S;

    const int s   = blockIdx.y;
    const int tid = threadIdx.x;

    // ---- stage this state's weights into LDS (coalesced) ----
    {
        const float* w0 = W0 + s * W0_PER_S;
        #pragma unroll
        for (int k = 0; k < 3; ++k) sW0[tid + 256 * k] = w0[tid + 256 * k];
        const float* w1 = W1 + s * W1_PER_S;
        #pragma unroll
        for (int k = 0; k < 16; ++k) sW1[tid + 256 * k] = w1[tid + 256 * k];
        if (tid < 64) sW2[tid] = W2[s * W2_PER_S + tid];
    }
    __syncthreads();

    const int b = blockIdx.x * 256 + tid;
    if (b >= nb) return;

    // ---- build z[12]: 8 selected x_tilde entries (sorted IDX[s]) + 4 u ----
    // IDX[s] sorted = {0..wrap-1} ++ {s..15} with wrap = max(0, s-8);
    // entry j: idx = (j < wrap) ? j : s + j - wrap. idx<8 -> x_f, else x_b.
    float z[12];
    const int wrap = (s > 8) ? (s - 8) : 0;
    #pragma unroll
    for (int j = 0; j < 8; ++j) {
        int idx = (j < wrap) ? j : (s + j - wrap);   // wave-uniform
        z[j] = (idx < 8) ? x_f[b * 8 + idx] : x_b[b * 8 + (idx - 8)];
    }
    const float4 uv = *(const float4*)(u + b * 4);
    z[8] = uv.x; z[9] = uv.y; z[10] = uv.z; z[11] = uv.w;

    // ---- layer 1: h1[o] = tanh(sum_i z[i] * W0[s][o][i]) ----
    // FULL unroll: every h1 index must be a compile-time constant so the
    // array lives in VGPRs (partial unroll here caused the R1 scratch spill).
    float h1[N_FEAT];
    #pragma unroll
    for (int o = 0; o < N_FEAT; ++o) {
        const float4* w = (const float4*)(sW0 + o * ZIN);  // 48B stride, 16B aligned
        float4 wa = w[0], wb = w[1], wc = w[2];
        float a0 = z[0] * wa.x;
        float a1 = z[1] * wa.y;
        float a2 = z[2] * wa.z;
        a0 = __builtin_fmaf(z[3],  wa.w, a0);
        a1 = __builtin_fmaf(z[4],  wb.x, a1);
        a2 = __builtin_fmaf(z[5],  wb.y, a2);
        a0 = __builtin_fmaf(z[6],  wb.z, a0);
        a1 = __builtin_fmaf(z[7],  wb.w, a1);
        a2 = __builtin_fmaf(z[8],  wc.x, a2);
        a0 = __builtin_fmaf(z[9],  wc.y, a0);
        a1 = __builtin_fmaf(z[10], wc.z, a1);
        a2 = __builtin_fmaf(z[11], wc.w, a2);
        h1[o] = fast_tanh(a0 + a1 + a2);
    }

    // ---- layer 2 + output dot: dx = sum_o tanh(<h1, W1[s][o]>) * W2[s][o] ----
    // Loop (not fully unrolled): all h1 reads are constant-indexed (4q+j), so
    // register promotion is safe; keeps code size I-cache friendly.
    float dx = 0.0f;
    #pragma unroll 2
    for (int o = 0; o < N_FEAT; ++o) {
        const float4* w = (const float4*)(sW1 + o * N_FEAT);  // 256B aligned
        float a0 = 0.f, a1 = 0.f, a2 = 0.f, a3 = 0.f;
        #pragma unroll
        for (int q = 0; q < 16; ++q) {
            float4 wv = w[q];
            a0 = __builtin_fmaf(h1[4 * q + 0], wv.x, a0);
            a1 = __builtin_fmaf(h1[4 * q + 1], wv.y, a1);
            a2 = __builtin_fmaf(h1[4 * q + 2], wv.z, a2);
            a3 = __builtin_fmaf(h1[4 * q + 3], wv.w, a3);
        }
        float hv = fast_tanh((a0 + a1) + (a2 + a3));
        dx = __builtin_fmaf(hv, sW2[o], dx);
    }

    out[b * N_STATES + s] = dx;
}

extern "C" void kernel_launch(void* const* d_in, const int* in_sizes, int n_in,
                              void* d_out, int out_size, void* d_ws, size_t ws_size,
                              hipStream_t stream) {
    const float* x_f = (const float*)d_in[0];
    const float* x_b = (const float*)d_in[1];
    const float* u   = (const float*)d_in[2];
    const float* W0  = (const float*)d_in[3];
    const float* W1  = (const float*)d_in[4];
    const float* W2  = (const float*)d_in[5];
    float* out = (float*)d_out;

    const int nb = in_sizes[0] / 8;                 // B = 131072
    dim3 grid((nb + 255) / 256, N_STATES);
    fans_kernel<<<grid, 256, 0, stream>>>(x_f, x_b, u, W0, W1, W2, out, nb);
}

// Round 4
// 197.252 us; speedup vs baseline: 2.6662x; 2.2954x over previous
//
#include <hip/hip_runtime.h>

// FANS: B=131072 rows x 16 states, MLP 12->64->64->1 with tanh, fp32 in/out.
// R4 = R3 with compile fix: cvt_pkrtz returns __fp16x2 -> bit-cast via union.
// f16 MFMA (fp32 accum) for both layers, transposed formulation:
//   H^T  = W0 . z^T   (m=feat, n=batch-row)  -> tanh -> pair-pack f16 -> LDS
//   H2^T = W1 . H^T   (B-frags read back as ds_read_b128)
//   dx   = sum_o tanh(H2^T)[o][row] * W2[o]  (VALU + 2x shfl_xor reduce)
// Per 16-row tile: 1 z b128 read + 4 mfma + 4 b64 writes + 2 b128 reads +
// 8 mfma + 32 tanh. No __syncthreads (each wave reads only LDS it wrote).
// Weights -> register fragments once per block. Predicted floor: tanh VALU.

#define N_STATES 16

typedef _Float16 f16x8 __attribute__((ext_vector_type(8)));
typedef float    f32x4 __attribute__((ext_vector_type(4)));

__device__ __forceinline__ unsigned int pack_f16(float a, float b) {
    // v_cvt_pkrtz_f16_f32 -> one packed dword
    auto p = __builtin_amdgcn_cvt_pkrtz(a, b);          // __fp16 ext_vector(2)
    union { decltype(p) h; unsigned int u; } cv{p};
    return cv.u;
}

__device__ __forceinline__ float fast_tanh(float x) {
    // tanh(x) = 1 - 2/(exp(2x)+1); exact saturation, ~1e-6 abs err
    float e = __builtin_amdgcn_exp2f(x * 2.885390081777927f);
    float r = __builtin_amdgcn_rcpf(e + 1.0f);
    return __builtin_fmaf(-2.0f, r, 1.0f);
}

__global__ __launch_bounds__(256) void fans_mfma_kernel(
    const float* __restrict__ x_f, const float* __restrict__ x_b,
    const float* __restrict__ u,   const float* __restrict__ W0,
    const float* __restrict__ W1,  const float* __restrict__ W2,
    float* __restrict__ out)
{
    // z staging: 256 rows x 16 f16 (32B rows, 16B-aligned frag reads)
    __shared__ __align__(16) _Float16 zbuf[256][16];            // 8 KB
    // H^T pair-packed: per wave, [row c][40 dwords]; dword P holds feats (2P,2P+1)
    __shared__ __align__(16) unsigned int Hd[4][16][40];        // 10 KB

    const int s   = blockIdx.y;
    const int tid = threadIdx.x;
    const int b0  = blockIdx.x * 256;

    // ---------------- phase 1: build z rows in LDS (f16) ----------------
    {
        const int row = b0 + tid;
        const float4 xf0 = ((const float4*)(x_f + row * 8))[0];
        const float4 xf1 = ((const float4*)(x_f + row * 8))[1];
        const float4 xb0 = ((const float4*)(x_b + row * 8))[0];
        const float4 xb1 = ((const float4*)(x_b + row * 8))[1];
        const float4 uv  = *(const float4*)(u + row * 4);

        const float xt[16] = {xf0.x, xf0.y, xf0.z, xf0.w, xf1.x, xf1.y, xf1.z, xf1.w,
                              xb0.x, xb0.y, xb0.z, xb0.w, xb1.x, xb1.y, xb1.z, xb1.w};
        // IDX[s] sorted = {0..wrap-1} ++ {s..min(s+7,15)}, wrap = max(0, s-8).
        // Scatter source i -> slot p (conditions wave-uniform: s is blockIdx.y).
        const int wrap = (s > 8) ? (s - 8) : 0;
        #pragma unroll
        for (int i = 0; i < 16; ++i) {
            const bool sel = (i < wrap) || (i >= s && i < s + 8);
            if (sel) {
                const int p = (i < wrap) ? i : (i - s + wrap);
                zbuf[tid][p] = (_Float16)xt[i];
            }
        }
        *(uint2*)&zbuf[tid][8]  = make_uint2(pack_f16(uv.x, uv.y),
                                             pack_f16(uv.z, uv.w));   // u[0..3]
        *(uint2*)&zbuf[tid][12] = make_uint2(0u, 0u);                 // z[12..15]=0
    }

    // ---------------- per-lane ids ----------------
    const int lid = tid & 63;
    const int w   = tid >> 6;     // wave id; wave w owns rows [64w, 64w+64)
    const int c   = lid & 15;     // MFMA "lane&15" index
    const int q   = lid >> 4;     // quad

    // ---------------- weight fragments (once per block) ----------------
    // Layer1 A-frags: A[m = feat 16t+c][k = 8q+j] = W0[s][o][k], k<12 else 0
    f16x8 a0[4];
    {
        const float* w0s = W0 + s * 768;
        #pragma unroll
        for (int t = 0; t < 4; ++t) {
            #pragma unroll
            for (int j = 0; j < 8; ++j) {
                const int k = 8 * q + j;
                const float v = (k < 12) ? w0s[(16 * t + c) * 12 + k] : 0.0f;
                a0[t][j] = (_Float16)v;
            }
        }
    }
    // Layer2 A-frags: A[m = feat_out 16t+c][k = 32ks+8q+j] = W1[s][o][h]
    f16x8 a1[2][4];
    {
        const float* w1s = W1 + s * 4096;
        #pragma unroll
        for (int ks = 0; ks < 2; ++ks) {
            #pragma unroll
            for (int t = 0; t < 4; ++t) {
                const float4* p = (const float4*)(w1s + (16 * t + c) * 64 + 32 * ks + 8 * q);
                const float4 v0 = p[0], v1 = p[1];
                a1[ks][t] = (f16x8){(_Float16)v0.x, (_Float16)v0.y, (_Float16)v0.z, (_Float16)v0.w,
                                    (_Float16)v1.x, (_Float16)v1.y, (_Float16)v1.z, (_Float16)v1.w};
            }
        }
    }
    // W2 values this lane needs: feat = 16t + 4q + r
    float w2v[16];
    {
        const float* w2s = W2 + s * 64;
        #pragma unroll
        for (int t = 0; t < 4; ++t)
            #pragma unroll
            for (int r = 0; r < 4; ++r)
                w2v[4 * t + r] = w2s[16 * t + 4 * q + r];
    }

    // ---------------- phase 2: 4 M-tiles of 16 rows per wave ----------------
    #pragma unroll
    for (int m = 0; m < 4; ++m) {
        const int rowb = 64 * w + 16 * m;   // local row base of this tile

        // z B-frag: B[k = 8q+j][n = row c] ; k>=16 (quads 2,3) is zero
        f16x8 zf = {0, 0, 0, 0, 0, 0, 0, 0};
        if (q < 2) zf = *(const f16x8*)&zbuf[rowb + c][8 * q];

        // layer 1: H^T tiles, C[row=feat 16t+4q+r][col=batch row c]
        f32x4 c1[4];
        #pragma unroll
        for (int t = 0; t < 4; ++t)
            c1[t] = __builtin_amdgcn_mfma_f32_16x16x32_f16(a0[t], zf, (f32x4){0.f, 0.f, 0.f, 0.f}, 0, 0, 0);

        // tanh -> pair-pack f16 -> LDS: dword P = 8t+2q holds feats (16t+4q+0, +1)
        #pragma unroll
        for (int t = 0; t < 4; ++t) {
            *(uint2*)&Hd[w][c][8 * t + 2 * q] =
                make_uint2(pack_f16(fast_tanh(c1[t][0]), fast_tanh(c1[t][1])),
                           pack_f16(fast_tanh(c1[t][2]), fast_tanh(c1[t][3])));
        }

        // layer 2: B-frag[k = 32ks+8q+j][n = c] = dwords P = 16ks+4q+0..3
        f32x4 c2[4] = {{0.f, 0.f, 0.f, 0.f}, {0.f, 0.f, 0.f, 0.f},
                       {0.f, 0.f, 0.f, 0.f}, {0.f, 0.f, 0.f, 0.f}};
        #pragma unroll
        for (int ks = 0; ks < 2; ++ks) {
            const uint4 hv = *(const uint4*)&Hd[w][c][16 * ks + 4 * q];
            union { uint4 v; f16x8 h; } bb{hv};
            #pragma unroll
            for (int t = 0; t < 4; ++t)
                c2[t] = __builtin_amdgcn_mfma_f32_16x16x32_f16(a1[ks][t], bb.h, c2[t], 0, 0, 0);
        }

        // layer 3: dx[row c] = sum_feat tanh(h2) * W2 ; reduce over quads
        float acc = 0.0f;
        #pragma unroll
        for (int t = 0; t < 4; ++t)
            #pragma unroll
            for (int r = 0; r < 4; ++r)
                acc = __builtin_fmaf(fast_tanh(c2[t][r]), w2v[4 * t + r], acc);
        acc += __shfl_xor(acc, 16);
        acc += __shfl_xor(acc, 32);

        if (lid < 16)
            out[(b0 + rowb + lid) * N_STATES + s] = acc;
    }
}

extern "C" void kernel_launch(void* const* d_in, const int* in_sizes, int n_in,
                              void* d_out, int out_size, void* d_ws, size_t ws_size,
                              hipStream_t stream) {
    const float* x_f = (const float*)d_in[0];
    const float* x_b = (const float*)d_in[1];
    const float* u   = (const float*)d_in[2];
    const float* W0  = (const float*)d_in[3];
    const float* W1  = (const float*)d_in[4];
    const float* W2  = (const float*)d_in[5];
    float* out = (float*)d_out;

    const int nb = in_sizes[0] / 8;          // 131072, multiple of 256
    dim3 grid(nb / 256, N_STATES);
    fans_mfma_kernel<<<grid, 256, 0, stream>>>(x_f, x_b, u, W0, W1, W2, out);
}

// Round 6
// 147.665 us; speedup vs baseline: 3.5616x; 1.3358x over previous
//
#include <hip/hip_runtime.h>

// FANS: B=131072 rows x 16 states, MLP 12->64->64->1 with tanh, fp32 in/out.
// R6 = R5 resubmitted verbatim (R5 bench was an infra failure: container died
// twice before running; no signal). R5 rationale:
// latency fixes on the R4 MFMA structure (R4: VALU 54 / MFMA 7 / occ 31 ->
// latency-bound; 1.1e7 LDS conflict cycles).
//  - CHUNK=8: block handles 2048 rows of one state -> 1024 blocks (4/CU, one
//    generation); weight-fragment gather amortized 8x (was once per 4 tiles).
//  - z staged via per-thread global gather (uniform branches, L1-resident) ->
//    register pack -> 2x ds_write_b128 into two-plane zbuf (row stride 16B ->
//    bank quad = c mod 8, min-spread). No f16 scatter writes.
//  - Hd row stride 40 -> 36 dwords (144B): read banks (4c+4q)%32 min-spread.
// No __syncthreads anywhere: every LDS row is written and read by the same wave.

#define N_STATES 16
#define CHUNK    8

typedef _Float16 f16x8 __attribute__((ext_vector_type(8)));
typedef float    f32x4 __attribute__((ext_vector_type(4)));

__device__ __forceinline__ unsigned int pack_f16(float a, float b) {
    auto p = __builtin_amdgcn_cvt_pkrtz(a, b);          // __fp16 ext_vector(2)
    union { decltype(p) h; unsigned int u; } cv{p};
    return cv.u;
}

__device__ __forceinline__ float fast_tanh(float x) {
    // tanh(x) = 1 - 2/(exp(2x)+1); exact saturation, ~1e-6 abs err
    float e = __builtin_amdgcn_exp2f(x * 2.885390081777927f);
    float r = __builtin_amdgcn_rcpf(e + 1.0f);
    return __builtin_fmaf(-2.0f, r, 1.0f);
}

__global__ __launch_bounds__(256, 4) void fans_mfma_kernel(
    const float* __restrict__ x_f, const float* __restrict__ x_b,
    const float* __restrict__ u,   const float* __restrict__ W0,
    const float* __restrict__ W1,  const float* __restrict__ W2,
    float* __restrict__ out)
{
    // z planes: plane q (0/1) holds dwords [4q..4q+3] of each row's 16 f16.
    // Row stride 16B -> b128 reads hit bank-quad (row mod 8): min-spread.
    __shared__ __align__(16) uint4 zpl[2 * 256];               // 8 KB
    // H^T pair-packed, row stride 36 dwords (144B): read banks (4c+4q)%32.
    __shared__ __align__(16) unsigned int Hd[4][16][36];       // 9 KB

    const int s   = blockIdx.y;
    const int tid = threadIdx.x;
    const int b0  = blockIdx.x * (256 * CHUNK);

    const int lid = tid & 63;
    const int w   = tid >> 6;     // wave id; wave w owns local rows [64w,64w+64)
    const int c   = lid & 15;
    const int q   = lid >> 4;

    // ---------------- weight fragments (once per block, amortized 8x) -------
    // Layer1 A-frag: A[m = feat 16t+c][k = 8q+j] = W0[s][feat][k], k<12 else 0
    f16x8 a0[4];
    {
        const float* w0s = W0 + s * 768;
        #pragma unroll
        for (int t = 0; t < 4; ++t) {
            #pragma unroll
            for (int j = 0; j < 8; ++j) {
                const int k = 8 * q + j;
                const float v = (k < 12) ? w0s[(16 * t + c) * 12 + k] : 0.0f;
                a0[t][j] = (_Float16)v;
            }
        }
    }
    // Layer2 A-frag: A[m = feat_out 16t+c][k = 32ks+8q+j] = W1[s][o][h]
    f16x8 a1[2][4];
    {
        const float* w1s = W1 + s * 4096;
        #pragma unroll
        for (int ks = 0; ks < 2; ++ks) {
            #pragma unroll
            for (int t = 0; t < 4; ++t) {
                const float4* p = (const float4*)(w1s + (16 * t + c) * 64 + 32 * ks + 8 * q);
                const float4 v0 = p[0], v1 = p[1];
                a1[ks][t] = (f16x8){(_Float16)v0.x, (_Float16)v0.y, (_Float16)v0.z, (_Float16)v0.w,
                                    (_Float16)v1.x, (_Float16)v1.y, (_Float16)v1.z, (_Float16)v1.w};
            }
        }
    }
    // W2 values this lane touches: feat = 16t + 4q + r
    float w2v[16];
    {
        const float* w2s = W2 + s * 64;
        #pragma unroll
        for (int t = 0; t < 4; ++t)
            #pragma unroll
            for (int r = 0; r < 4; ++r)
                w2v[4 * t + r] = w2s[16 * t + 4 * q + r];
    }

    const int wrap = (s > 8) ? (s - 8) : 0;   // IDX[s] = {0..wrap-1}++{s..15}

    #pragma unroll 1
    for (int ch = 0; ch < CHUNK; ++ch) {
        const int rbase = b0 + ch * 256;

        // ---- phase 1: gather z for own row, pack, 2x b128 into planes ----
        {
            const int row = rbase + tid;
            float zs[8];
            #pragma unroll
            for (int j = 0; j < 8; ++j) {
                const int idx = (j < wrap) ? j : (s + j - wrap);  // uniform
                zs[j] = (idx < 8) ? x_f[row * 8 + idx] : x_b[row * 8 + (idx - 8)];
            }
            const float4 uv = *(const float4*)(u + row * 4);
            zpl[tid] = make_uint4(pack_f16(zs[0], zs[1]), pack_f16(zs[2], zs[3]),
                                  pack_f16(zs[4], zs[5]), pack_f16(zs[6], zs[7]));
            zpl[256 + tid] = make_uint4(pack_f16(uv.x, uv.y), pack_f16(uv.z, uv.w), 0u, 0u);
        }

        // ---- phase 2: 4 M-tiles of 16 rows (own wave's rows only) ----
        #pragma unroll
        for (int m = 0; m < 4; ++m) {
            const int rowb = 64 * w + 16 * m;

            // z B-frag: B[k = 8q+j][n = row c]; quads 2,3 are zero (K pad)
            f16x8 zf = {0, 0, 0, 0, 0, 0, 0, 0};
            if (q < 2) {
                const uint4 zv = zpl[q * 256 + rowb + c];
                union { uint4 v; f16x8 h; } cz{zv};
                zf = cz.h;
            }

            // layer 1: C[row = feat 16t+4q+r][col = batch row c]
            f32x4 c1[4];
            #pragma unroll
            for (int t = 0; t < 4; ++t)
                c1[t] = __builtin_amdgcn_mfma_f32_16x16x32_f16(
                    a0[t], zf, (f32x4){0.f, 0.f, 0.f, 0.f}, 0, 0, 0);

            // tanh -> pack -> LDS: dword P = 8t+2q holds feats (16t+4q, +1)
            #pragma unroll
            for (int t = 0; t < 4; ++t) {
                *(uint2*)&Hd[w][c][8 * t + 2 * q] =
                    make_uint2(pack_f16(fast_tanh(c1[t][0]), fast_tanh(c1[t][1])),
                               pack_f16(fast_tanh(c1[t][2]), fast_tanh(c1[t][3])));
            }

            // layer 2: B-frag[k = 32ks+8q+j][n = c] = dwords 16ks+4q+0..3
            f32x4 c2[4] = {{0.f, 0.f, 0.f, 0.f}, {0.f, 0.f, 0.f, 0.f},
                           {0.f, 0.f, 0.f, 0.f}, {0.f, 0.f, 0.f, 0.f}};
            #pragma unroll
            for (int ks = 0; ks < 2; ++ks) {
                const uint4 hv = *(const uint4*)&Hd[w][c][16 * ks + 4 * q];
                union { uint4 v; f16x8 h; } bb{hv};
                #pragma unroll
                for (int t = 0; t < 4; ++t)
                    c2[t] = __builtin_amdgcn_mfma_f32_16x16x32_f16(a1[ks][t], bb.h, c2[t], 0, 0, 0);
            }

            // layer 3: dx[row c] = sum_feat tanh(h2) * W2; reduce over quads
            float acc = 0.0f;
            #pragma unroll
            for (int t = 0; t < 4; ++t)
                #pragma unroll
                for (int r = 0; r < 4; ++r)
                    acc = __builtin_fmaf(fast_tanh(c2[t][r]), w2v[4 * t + r], acc);
            acc += __shfl_xor(acc, 16);
            acc += __shfl_xor(acc, 32);

            if (lid < 16)
                out[(rbase + rowb + lid) * N_STATES + s] = acc;
        }
    }
}

extern "C" void kernel_launch(void* const* d_in, const int* in_sizes, int n_in,
                              void* d_out, int out_size, void* d_ws, size_t ws_size,
                              hipStream_t stream) {
    const float* x_f = (const float*)d_in[0];
    const float* x_b = (const float*)d_in[1];
    const float* u   = (const float*)d_in[2];
    const float* W0  = (const float*)d_in[3];
    const float* W1  = (const float*)d_in[4];
    const float* W2  = (const float*)d_in[5];
    float* out = (float*)d_out;

    const int nb = in_sizes[0] / 8;                 // 131072 = 64 * 2048
    dim3 grid(nb / (256 * CHUNK), N_STATES);        // (64, 16) = 1024 blocks
    fans_mfma_kernel<<<grid, 256, 0, stream>>>(x_f, x_b, u, W0, W1, W2, out);
}